// Round 4
// baseline (278.105 us; speedup 1.0000x reference)
//
#include <hip/hip_runtime.h>

// DualModel3 R9: 4x independent barrier-groups per CU.
// R5 (93us), R6 (101us), R8 (99us) have structurally different iteration
// bodies (reg-staged / deep-pipelined / GLDS) but identical ~7k cyc per
// K-iteration, with every pipe idle (LDS ~17%, HBM 10%, MFMA ~2%, conflicts
// 7%). The invariant: 544 blocks = 2.1 independent barrier-groups/CU. R6
// doubled waves/CU but kept them lockstep on the SAME barrier -> null. The
// per-iter latency chain (W1 ~900cyc HBM + L2 trips + barrier convergence)
// is only hidden by waves in a DIFFERENT group.
// R9: BM=64 x BN=64, 128-thr blocks (2 waves) -> 1088 blocks = 4.25
// groups/CU (LDS 32KB -> 5 resident; all co-resident). Per-wave iteration
// density unchanged (12 ds_read_b128 + 8 MFMA) = clean A/B of the theory.
// Grid order: 4 rg-siblings of a cg adjacent -> W1 slab served 4x from the
// same XCD L2 (HBM FETCH unchanged ~74MB). B-writes now 4x ds_write_b128
// per thread (thread owns a full k-group). launch_bounds(128,2): VGPR cap
// 256 -> no spill (R6 lesson).
// Verified invariants kept: pack_tiles byte-images (A slot=g^(r&7), fc
// slot=g^((n>>2)&7)), 32x32x16 MFMA, C/D col=lane&31,
// row=(r&3)+8*(r>>2)+4*(lane>>5), XCD-bijective swizzle (1088%8==0).

typedef __bf16 bf16_t;
typedef __bf16 bf16x8 __attribute__((ext_vector_type(8)));
typedef float  f32x4  __attribute__((ext_vector_type(4)));
typedef float  f32x16 __attribute__((ext_vector_type(16)));

#define GLDS(gp, lp) __builtin_amdgcn_global_load_lds( \
    (const __attribute__((address_space(1))) void*)(gp), \
    (__attribute__((address_space(3))) void*)(lp), 16, 0, 0)

#define WS_A_OFF 0                          // 64 tiles  x 16KB = 1 MB
#define WS_F_OFF (64 * 16384)               // 512 tiles x 8KB  = 4 MB (tot 5 MB)

// ---------------------------------------------------------------- pass 1 ----
// (unchanged from R8 — verified correct)
// A image: row r (128B), slot s holds k-group g = s ^ (r&7), 8 bf16 each.
// fc image: row n (128B), slot s holds k-group g = s ^ ((n>>2)&7).
__global__ __launch_bounds__(256)
void pack_tiles(const float* __restrict__ x, const float* __restrict__ fcW,
                char* __restrict__ ws)
{
    const int tid = threadIdx.x;
    const int bid = blockIdx.x;
    if (bid < 64) {                                   // x tiles: [rg2][kt] 16KB
        const int rg = bid >> 5, kt = bid & 31;
        char* dst = ws + WS_A_OFF + (size_t)bid * 16384;
        #pragma unroll
        for (int i = 0; i < 4; ++i) {
            const int gi = tid + 256 * i;
            const int r = gi >> 3, s = gi & 7, g = s ^ (r & 7);
            const float* sp = x + (size_t)(rg * 128 + r) * 2048 + kt * 64 + g * 8;
            f32x4 v0 = *(const f32x4*)sp, v1 = *(const f32x4*)(sp + 4);
            bf16x8 o;
            #pragma unroll
            for (int c = 0; c < 4; ++c) { o[c] = (bf16_t)v0[c]; o[4 + c] = (bf16_t)v1[c]; }
            *(bf16x8*)(dst + r * 128 + s * 16) = o;
        }
    } else {                                          // fcW tiles: [cg][kt] 8KB
        const int t = bid - 64;
        const int cg = t >> 5, kt = t & 31;
        char* dst = ws + WS_F_OFF + (size_t)t * 8192;
        #pragma unroll
        for (int i = 0; i < 2; ++i) {
            const int gi = tid + 256 * i;
            const int n = gi >> 3, s = gi & 7, g = s ^ ((n >> 2) & 7);
            const int c = cg * 64 + n;
            bf16x8 o;
            if (c < 1000) {
                const float* sp = fcW + (size_t)c * 2048 + kt * 64 + g * 8;
                f32x4 v0 = *(const f32x4*)sp, v1 = *(const f32x4*)(sp + 4);
                #pragma unroll
                for (int cc = 0; cc < 4; ++cc) { o[cc] = (bf16_t)v0[cc]; o[4 + cc] = (bf16_t)v1[cc]; }
            } else {
                #pragma unroll
                for (int cc = 0; cc < 8; ++cc) o[cc] = (bf16_t)0.f;
            }
            *(bf16x8*)(dst + n * 128 + s * 16) = o;
        }
    }
}

// ---------------------------------------------------------------- pass 2 ----
__global__ __launch_bounds__(128, 2)    // VGPR cap 256: no spill; LDS 32KB -> 5 blk/CU
void fused_dual(const char* __restrict__ ws,
                const float* __restrict__ W1,   // [4096,2048,4] fp32
                const float* __restrict__ fcb,
                const float* __restrict__ b1,
                const float* __restrict__ W2,
                const float* __restrict__ b2,
                float* __restrict__ out)        // x1[256*1000] ++ x2[256*4096]
{
    __shared__ __align__(16) char lds[2][16384];   // [buf][A 8KB | B 8KB]

    const int tid  = threadIdx.x;
    const int lane = tid & 63, w = tid >> 6;       // 2 waves
    const int l31  = lane & 31, half = lane >> 5;

    // XCD swizzle: 1088 = 8 x 136, bijective. cg-major: 4 rg-siblings of a cg
    // are adjacent -> same XCD -> W1 slab L2-reuse (read 4x, fetched once).
    const int idx = blockIdx.x;
    const int wid = (idx & 7) * 136 + (idx >> 3);
    const int cg  = wid >> 2, rg = wid & 3, m0 = rg * 64;
    const bool is_fc = (cg < 16);
    const int c0  = (is_fc ? cg : cg - 16) * 64;
    const int dcg = is_fc ? 0 : (cg - 16);

    // A slice: packed tile rg>>1 (128 rows), rows (rg&1)*64..+63 (8KB linear).
    const char* aT = ws + WS_A_OFF + (size_t)(rg >> 1) * 32 * 16384 + (rg & 1) * 8192;
    const char* bT = ws + WS_F_OFF + (size_t)cg * 32 * 8192;    // fc only

    const int lo = lane * 16;   // per-lane global offset; GLDS dest wave-uniform

    // ---- decoder B staging map (128 thr) ----
    // thread: oloc = tid>>3 (o in panel, 0..15), gg = tid&7 (k-group).
    // loads: W1[o0+oloc][k0 + gg*8 + j][0..3], j=0..7  (thread covers its full
    //        k-group; 8x f32x4, thread-contiguous 128B).
    // writes: per h: row n=4*oloc+h, slot=gg^(oloc&7), FULL 16B b128 write.
    const int oloc = tid >> 3, gg = tid & 7;
    const float* w1Base = W1 + (size_t)(dcg * 16 + oloc) * 8192 + gg * 32;
    const int wbase = (4 * oloc) * 128 + (gg ^ (oloc & 7)) * 16;

    f32x4 bReg[8];

    auto B_LOAD = [&](int kt) {
        const float* p = w1Base + kt * 256;                 // 64 k * 4 floats
        #pragma unroll
        for (int j = 0; j < 8; ++j) bReg[j] = *(const f32x4*)(p + j * 4);
    };
    auto B_WRITE = [&](int pbuf) {
        char* lB = &lds[pbuf][8192];
        #pragma unroll
        for (int h = 0; h < 4; ++h) {
            bf16x8 v;
            #pragma unroll
            for (int j = 0; j < 8; ++j) v[j] = (bf16_t)bReg[j][h];
            *(bf16x8*)(lB + wbase + h * 128) = v;
        }
    };
    auto GLDS_A = [&](int kt, int pbuf) {
        char* lA = &lds[pbuf][0];
        const char* ga = aT + (size_t)kt * 16384 + w * 4096;
        #pragma unroll
        for (int i = 0; i < 4; ++i)
            GLDS(ga + i * 1024 + lo, lA + w * 4096 + i * 1024);
    };
    auto GLDS_B_FC = [&](int kt, int pbuf) {
        char* lB = &lds[pbuf][8192];
        const char* gb = bT + (size_t)kt * 8192 + w * 4096;
        #pragma unroll
        for (int i = 0; i < 4; ++i)
            GLDS(gb + i * 1024 + lo, lB + w * 4096 + i * 1024);
    };

    // wave tile: 32m x 64n. mrow per wave; acc[i] over n-halves.
    const int mh = w * 32;
    f32x16 acc[2];
    #pragma unroll
    for (int i = 0; i < 2; ++i)
        #pragma unroll
        for (int r = 0; r < 16; ++r) acc[i][r] = 0.f;

    // prologue: tile 0 into buf 0
    if (is_fc) {
        GLDS_A(0, 0); GLDS_B_FC(0, 0);
    } else {
        B_LOAD(0); GLDS_A(0, 0); B_WRITE(0);
    }
    __syncthreads();

    const int mrow = mh + l31;
    for (int kt = 0; kt < 32; ++kt) {
        const int p = kt & 1;
        if (kt < 31) {                       // next tile: loads span the MFMA phase
            if (is_fc) { GLDS_A(kt + 1, p ^ 1); GLDS_B_FC(kt + 1, p ^ 1); }
            else       { B_LOAD(kt + 1); GLDS_A(kt + 1, p ^ 1); }
        }
        const char* lA = &lds[p][0];
        const char* lB = &lds[p][8192];
        __builtin_amdgcn_s_setprio(1);
        #pragma unroll
        for (int ks = 0; ks < 4; ++ks) {
            const int g = ks * 2 + half;
            bf16x8 af = *(const bf16x8*)(lA + mrow * 128 + ((g ^ (mrow & 7)) << 4));
            #pragma unroll
            for (int i = 0; i < 2; ++i) {
                const int nrow = i * 32 + l31;
                bf16x8 bf = *(const bf16x8*)(lB + nrow * 128 + ((g ^ ((nrow >> 2) & 7)) << 4));
                acc[i] = __builtin_amdgcn_mfma_f32_32x32x16_bf16(af, bf, acc[i], 0, 0, 0);
            }
        }
        __builtin_amdgcn_s_setprio(0);
        if (!is_fc && kt < 31) B_WRITE(p ^ 1);  // auto-vmcnt waits only bReg's loads
        __syncthreads();
    }

    // ---- epilogue ----  C/D: col=lane&31, row=(r&3)+8*(r>>2)+4*half
    if (is_fc) {
        #pragma unroll
        for (int i = 0; i < 2; ++i) {
            const int c = c0 + i * 32 + l31;
            if (c < 1000) {
                const float bias = fcb[c];
                #pragma unroll
                for (int r = 0; r < 16; ++r) {
                    const int m = m0 + mh + (r & 3) + 8 * (r >> 2) + 4 * half;
                    out[m * 1000 + c] = acc[i][r] + bias;
                }
            }
        }
    } else {
        float* x2 = out + 256 * 1000;
        const int d = cg - 16;                    // decoder col-panel
        float* xs = (float*)lds;                  // [64 rows][16 o] fp32 = 4KB
        #pragma unroll
        for (int i = 0; i < 2; ++i) {
            const int n_glob = c0 + i * 32 + l31;
            const float b1v = b1[n_glob], w2v = W2[n_glob];
            const float b2v = b2[n_glob >> 2];
            const int o_loc = (i * 32 + l31) >> 2;
            #pragma unroll
            for (int r = 0; r < 16; ++r) {
                float h = acc[i][r] + b1v;
                h = (h >= 0.f) ? h : 0.1f * h;        // leaky relu
                float wv = h * w2v;
                wv += __shfl_xor(wv, 1, 64);          // decoder's 4 h-cols
                wv += __shfl_xor(wv, 2, 64);
                if ((lane & 3) == 0) {
                    const int row = mh + (r & 3) + 8 * (r >> 2) + 4 * half;
                    xs[row * 16 + o_loc] = wv + b2v;
                }
            }
        }
        __syncthreads();
        #pragma unroll
        for (int j = 0; j < 2; ++j) {
            const int row = (tid >> 2) + 32 * j, part = tid & 3;
            f32x4 v = *(const f32x4*)(xs + row * 16 + part * 4);
            *(f32x4*)(x2 + (m0 + row) * 4096 + d * 16 + part * 4) = v;
        }
    }
}

extern "C" void kernel_launch(void* const* d_in, const int* in_sizes, int n_in,
                              void* d_out, int out_size, void* d_ws, size_t ws_size,
                              hipStream_t stream)
{
    (void)in_sizes; (void)n_in; (void)out_size; (void)ws_size;
    const float* x   = (const float*)d_in[0];
    const float* fcW = (const float*)d_in[1];
    const float* fcb = (const float*)d_in[2];
    const float* W1  = (const float*)d_in[3];
    const float* b1  = (const float*)d_in[4];
    const float* W2  = (const float*)d_in[5];
    const float* b2  = (const float*)d_in[6];
    char* ws = (char*)d_ws;                       // 5 MB (proven R7/R8-safe)
    pack_tiles<<<576, 256, 0, stream>>>(x, fcW, ws);
    fused_dual<<<1088, 128, 0, stream>>>(ws, W1, fcb, b1, W2, b2, (float*)d_out);
}

// Round 5
// 267.255 us; speedup vs baseline: 1.0406x; 1.0406x over previous
//
#include <hip/hip_runtime.h>

// DualModel3 R10: W1 hoisted out of the K-loop.
// R5-R9 post-mortem: dur == FETCH_SIZE / hbm_gbps in every round, with BW
// stuck at 700-950 GB/s (11% of achievable). Cause: per K-iter each decoder
// block reads 16x 1KB chunks of W1 at 32KB stride; 512 blocks => ~8k
// interleaved 1KB HBM streams (DRAM page thrash) with a barrier draining
// vmcnt every iter => exposed multi-k-cycle latency. Scheduling variants
// (R6 occupancy, R8 GLDS, R9 block split) couldn't move it; the W1 READ
// PATTERN is the bottleneck.
// R10: BM=256 (full M, W1 read once chip-wide), BN=32 (8 decoders). B-panel
// lives in LDS for a half-K mega-phase: per phase one CONTIGUOUS 128KB W1
// burst per block (512B/thread), cvt to bf16 tile image once. K-loop reads
// B from LDS only; A streams via GLDS dbuf from the 1MB packed ws image
// (L2-resident per XCD). HBM is gone from the inner loop.
// LDS 128KB = B 16x4KB k-tiles + A dbuf 2x32KB (precedent: 8-phase template
// uses 128KiB static). 1 blk/CU, grid 544 = 512 dec (XCD-swizzled) + 32 fc
// (tail). B image swizzle upgraded: slot = g ^ (n&7) -> conflict-free B frag
// reads (pack fc image updated to match). A image + MFMA + C/D math
// unchanged (verified): 32x32x16, C/D col=lane&31, row=(r&3)+8*(r>>2)+4*half.

typedef __bf16 bf16_t;
typedef __bf16 bf16x8 __attribute__((ext_vector_type(8)));
typedef float  f32x4  __attribute__((ext_vector_type(4)));
typedef float  f32x16 __attribute__((ext_vector_type(16)));

#define GLDS(gp, lp) __builtin_amdgcn_global_load_lds( \
    (const __attribute__((address_space(1))) void*)(gp), \
    (__attribute__((address_space(3))) void*)(lp), 16, 0, 0)

#define WS_A_OFF 0                          // 64 tiles  x 16KB = 1 MB
#define WS_F_OFF (64 * 16384)               // 512 tiles x 8KB  = 4 MB (tot 5 MB)

// ---------------------------------------------------------------- pass 1 ----
// A image (verified): [rg2][kt32] tiles, row r 128B, slot s = g ^ (r&7).
// fc image (UPDATED): [cg16][kt32] tiles, row n 128B, slot s = g ^ (n&7).
__global__ __launch_bounds__(256)
void pack_tiles(const float* __restrict__ x, const float* __restrict__ fcW,
                char* __restrict__ ws)
{
    const int tid = threadIdx.x;
    const int bid = blockIdx.x;
    if (bid < 64) {                                   // x tiles (unchanged)
        const int rg = bid >> 5, kt = bid & 31;
        char* dst = ws + WS_A_OFF + (size_t)bid * 16384;
        #pragma unroll
        for (int i = 0; i < 4; ++i) {
            const int gi = tid + 256 * i;
            const int r = gi >> 3, s = gi & 7, g = s ^ (r & 7);
            const float* sp = x + (size_t)(rg * 128 + r) * 2048 + kt * 64 + g * 8;
            f32x4 v0 = *(const f32x4*)sp, v1 = *(const f32x4*)(sp + 4);
            bf16x8 o;
            #pragma unroll
            for (int c = 0; c < 4; ++c) { o[c] = (bf16_t)v0[c]; o[4 + c] = (bf16_t)v1[c]; }
            *(bf16x8*)(dst + r * 128 + s * 16) = o;
        }
    } else {                                          // fcW tiles, new swizzle
        const int t = bid - 64;
        const int cg = t >> 5, kt = t & 31;
        char* dst = ws + WS_F_OFF + (size_t)t * 8192;
        #pragma unroll
        for (int i = 0; i < 2; ++i) {
            const int gi = tid + 256 * i;
            const int n = gi >> 3, s = gi & 7, g = s ^ (n & 7);
            const int c = cg * 64 + n;
            bf16x8 o;
            if (c < 1000) {
                const float* sp = fcW + (size_t)c * 2048 + kt * 64 + g * 8;
                f32x4 v0 = *(const f32x4*)sp, v1 = *(const f32x4*)(sp + 4);
                #pragma unroll
                for (int cc = 0; cc < 4; ++cc) { o[cc] = (bf16_t)v0[cc]; o[4 + cc] = (bf16_t)v1[cc]; }
            } else {
                #pragma unroll
                for (int cc = 0; cc < 8; ++cc) o[cc] = (bf16_t)0.f;
            }
            *(bf16x8*)(dst + n * 128 + s * 16) = o;
        }
    }
}

// ---------------------------------------------------------------- pass 2 ----
__global__ __launch_bounds__(256, 1)    // 1 blk/CU (128KB LDS); VGPR free
void fused_dual(const char* __restrict__ ws,
                const float* __restrict__ W1,   // [4096,2048,4] fp32
                const float* __restrict__ fcb,
                const float* __restrict__ b1,
                const float* __restrict__ W2,
                const float* __restrict__ b2,
                float* __restrict__ out)        // x1[256*1000] ++ x2[256*4096]
{
    // [0,64K): B panel, 16 k-tiles x [32 rows x 128B]  (one half-K phase)
    // [64K,96K) + [96K,128K): A double buffer, each [256 rows x 128B] (64 k)
    __shared__ __align__(16) char lds[131072];
    char* lB = lds;

    const int tid  = threadIdx.x;
    const int lane = tid & 63, w = tid >> 6;       // 4 waves
    const int l31  = lane & 31, half = lane >> 5;

    // Grid: decoders 0..511 XCD-swizzled (512 = 8x64 bijective); fc 512..543
    // dispatched last (tail round gets the cheap blocks).
    const int idx = blockIdx.x;
    const int wid = (idx < 512) ? ((idx & 7) * 64 + (idx >> 3)) : idx;
    const bool is_fc = (wid >= 512);
    const int d   = wid;                 // decoder index (o0 = d*8)
    const int fcI = wid - 512;           // fc panel (c0 = fcI*32)

    // ---- decoder W1 slab mapping ----
    // thread t: o_loc = t&7; rounds r=0..3: idxk = (t>>3)*4+r selects one
    // k-group (8 k x 4 h = 128B contiguous) of o_loc within the phase half.
    // 512B contiguous per thread per phase; block = 128KB contiguous-ish.
    const int o_loc = tid & 7;
    const float* w1o = W1 + (size_t)(d * 8 + o_loc) * 8192;
    const int cbase = (tid >> 3) * 4;

    // ---- fc B source ----
    const int cgo = fcI >> 1, rowhalf = fcI & 1;
    const char* fcSrc = ws + WS_F_OFF + (size_t)cgo * 32 * 8192 + rowhalf * 4096;

    f32x4 rga[8], rgb[8];
    auto BL = [&](int kh, int r, f32x4* R) {
        const float* p = w1o + kh * 4096 + (cbase + r) * 32;
        #pragma unroll
        for (int j = 0; j < 8; ++j) R[j] = *(const f32x4*)(p + j * 4);
    };
    auto BW = [&](int r, const f32x4* R) {           // reg j = (k_local=j, h0..3)
        const int idxk = cbase + r;
        const int ktl = idxk >> 3, g = idxk & 7;
        char* base = lB + ktl * 4096 + (4 * o_loc) * 128;
        #pragma unroll
        for (int h = 0; h < 4; ++h) {
            bf16x8 v;
            #pragma unroll
            for (int j = 0; j < 8; ++j) v[j] = (bf16_t)R[j][h];
            const int n7 = (4 * o_loc + h) & 7;
            *(bf16x8*)(base + h * 128 + ((g ^ n7) << 4)) = v;
        }
    };

    auto GLDS_A = [&](int ktg, int pbuf) {           // 32KB: rg0 tile ++ rg1 tile
        char* dst = lds + 65536 + pbuf * 32768 + w * 8192;
        const char* src = ws + WS_A_OFF + (size_t)(w >> 1) * 524288
                        + (size_t)ktg * 16384 + (w & 1) * 8192 + lane * 16;
        #pragma unroll
        for (int i = 0; i < 8; ++i)
            GLDS(src + i * 1024, dst + i * 1024);
    };

    f32x16 acc[2];
    #pragma unroll
    for (int i = 0; i < 2; ++i)
        #pragma unroll
        for (int r = 0; r < 16; ++r) acc[i][r] = 0.f;

    for (int kh = 0; kh < 2; ++kh) {
        // ---- B slab phase: one contiguous 128KB burst (dec) / 64KB GLDS (fc)
        if (is_fc) {
            #pragma unroll
            for (int ktl = 0; ktl < 16; ++ktl)
                GLDS(fcSrc + (size_t)(kh * 16 + ktl) * 8192 + w * 1024 + lane * 16,
                     lB + ktl * 4096 + w * 1024);
        } else {
            BL(kh, 0, rga); BL(kh, 1, rgb);
            BW(0, rga);     BL(kh, 2, rga);
            BW(1, rgb);     BL(kh, 3, rgb);
            BW(2, rga);     BW(3, rgb);
        }
        GLDS_A(kh * 16, 0);
        __syncthreads();                 // drains vmcnt (GLDS) + lgkmcnt (ds_write)

        for (int ktl = 0; ktl < 16; ++ktl) {
            const int p = ktl & 1;
            if (ktl < 15) GLDS_A(kh * 16 + ktl + 1, p ^ 1);   // spans MFMA phase
            const char* A  = lds + 65536 + p * 32768;
            const char* Bt = lB + ktl * 4096;
            #pragma unroll
            for (int ks = 0; ks < 4; ++ks) {
                const int g = ks * 2 + half;
                bf16x8 bf = *(const bf16x8*)(Bt + l31 * 128 + ((g ^ (l31 & 7)) << 4));
                #pragma unroll
                for (int i = 0; i < 2; ++i) {
                    const int mrow = w * 64 + i * 32 + l31;
                    bf16x8 af = *(const bf16x8*)(A + mrow * 128 + ((g ^ (mrow & 7)) << 4));
                    acc[i] = __builtin_amdgcn_mfma_f32_32x32x16_bf16(af, bf, acc[i], 0, 0, 0);
                }
            }
            asm volatile("s_waitcnt vmcnt(0)" ::: "memory");  // A(p^1) landed
            __builtin_amdgcn_s_barrier();
            asm volatile("" ::: "memory");
        }
    }

    // ---- epilogue ----  C/D: col=lane&31, row=(r&3)+8*(r>>2)+4*half
    if (is_fc) {
        const int c = fcI * 32 + l31;
        if (c < 1000) {
            const float bias = fcb[c];
            #pragma unroll
            for (int i = 0; i < 2; ++i)
            #pragma unroll
            for (int r = 0; r < 16; ++r) {
                const int m = w * 64 + i * 32 + (r & 3) + 8 * (r >> 2) + 4 * half;
                out[m * 1000 + c] = acc[i][r] + bias;
            }
        }
    } else {
        float* x2 = out + 256 * 1000;
        const int n_glob = d * 32 + l31;
        const float b1v = b1[n_glob], w2v = W2[n_glob];
        const float b2v = b2[n_glob >> 2];
        float* xs = (float*)(lds + 65536);        // [256 rows][8 o] = 8KB
        const int o8 = l31 >> 2;
        #pragma unroll
        for (int i = 0; i < 2; ++i)
        #pragma unroll
        for (int r = 0; r < 16; ++r) {
            float h = acc[i][r] + b1v;
            h = (h >= 0.f) ? h : 0.1f * h;        // leaky relu
            float wv = h * w2v;
            wv += __shfl_xor(wv, 1, 64);          // decoder's 4 h-cols
            wv += __shfl_xor(wv, 2, 64);
            if ((lane & 3) == 0) {
                const int row = w * 64 + i * 32 + (r & 3) + 8 * (r >> 2) + 4 * half;
                xs[row * 8 + o8] = wv + b2v;
            }
        }
        __syncthreads();
        #pragma unroll
        for (int j = 0; j < 2; ++j) {
            const int row = (tid >> 1) + j * 128, part = tid & 1;
            f32x4 v = *(const f32x4*)(xs + row * 8 + part * 4);
            *(f32x4*)(x2 + (size_t)row * 4096 + d * 8 + part * 4) = v;
        }
    }
}

extern "C" void kernel_launch(void* const* d_in, const int* in_sizes, int n_in,
                              void* d_out, int out_size, void* d_ws, size_t ws_size,
                              hipStream_t stream)
{
    (void)in_sizes; (void)n_in; (void)out_size; (void)ws_size;
    const float* x   = (const float*)d_in[0];
    const float* fcW = (const float*)d_in[1];
    const float* fcb = (const float*)d_in[2];
    const float* W1  = (const float*)d_in[3];
    const float* b1  = (const float*)d_in[4];
    const float* W2  = (const float*)d_in[5];
    const float* b2  = (const float*)d_in[6];
    char* ws = (char*)d_ws;                       // 5 MB (proven safe)
    pack_tiles<<<576, 256, 0, stream>>>(x, fcW, ws);
    fused_dual<<<544, 256, 0, stream>>>(ws, W1, fcb, b1, W2, b2, (float*)d_out);
}

// Round 6
// 238.218 us; speedup vs baseline: 1.1674x; 1.1219x over previous
//
#include <hip/hip_runtime.h>

// DualModel3 R11: frag-major A stream (no LDS for A), barrier gates only B.
// R5-R10 post-mortem: all variants ~93-112us with every pipe <10%. The
// "dur=FETCH/BW" relation was a tautology; real diagnosis = latency
// serialization: per-iter vmcnt(0) drains + A staged behind a barrier each
// iter + <=2 independent blocks/CU (R10: 1/CU -> 2.1 sequential rounds + a
// 32-block tail round) + 256 CUs synchronously re-reading the SAME A-tile
// L2 lines (hotspot).
// R11 structural fixes:
//  - A image packed FRAG-MAJOR: [kt32][mchunk8][kgroup8][lane32 x 16B]. A
//    fragments load global->VGPR as perfectly coalesced dwordx4 (1KB/instr),
//    double-buffered 1 iter ahead in regs. No LDS, no swizzle, no barrier
//    dependency; compiler's counted vmcnt keeps them in flight ACROSS
//    barriers. 4 replicas (1MB each, ws total 4MB < proven-safe 5MB),
//    replica = XCD/2, to kill the L2 same-line storm.
//  - LDS = B-tile only (32n x 64k bf16 = 4KB, dbuf 8KB). B fp32 reg-loaded
//    TWO iters ahead (covers ~900cyc HBM latency), cvt+ds_write after the
//    MFMA phase, then lgkmcnt(0)+s_barrier ONLY (no VM drain in the loop).
//  - B LDS swizzle slot = g ^ (n&7) ^ (((n>>3)&3)<<1): granule index
//    8n+slot mod 32 distinct for n=0..31 at fixed g -> conflict-free b128
//    reads; writes land 2 lanes/bank (free, m136).
//  - 8KB LDS + ~145 VGPR -> 3 blocks/CU; all 544 blocks co-resident
//    (544 <= 768): zero dispatch rounds, zero tail.
// Grid: 512 decoder blocks (BN=32 = 8 decoders, BM=256 = full M -> W1 read
// once chip-wide) + 32 fc blocks (32 cols), XCD-bijective swizzle (544=8x68).
// MFMA math unchanged (verified R5-R10): 32x32x16, acc = mfma(aFrag,bFrag),
// C/D col=lane&31, row=(r&3)+8*(r>>2)+4*(lane>>5).

typedef __bf16 bf16_t;
typedef __bf16 bf16x2v __attribute__((ext_vector_type(2)));
typedef __bf16 bf16x8 __attribute__((ext_vector_type(8)));
typedef float  f32x4  __attribute__((ext_vector_type(4)));
typedef float  f32x16 __attribute__((ext_vector_type(16)));

#define WS_REP_BYTES (1 << 20)     // 1 MB per A replica, 4 replicas

__device__ __forceinline__ int bslot(int n, int g) {
    return g ^ (n & 7) ^ (((n >> 3) & 3) << 1);
}

// ---------------------------------------------------------------- pass 1 ----
// Frag-major A image: byte = rep*1MB + kt*32768 + gi*16, where
// gi = mchunk*256 + g*32 + lane31; lane-slot holds x[mchunk*32+l][kt*64+g*8..+7].
__global__ __launch_bounds__(256)
void pack_a(const float* __restrict__ x, char* __restrict__ ws)
{
    const int kt  = blockIdx.x & 31;
    const int rep = blockIdx.x >> 5;                  // 0..3
    char* dst = ws + (size_t)rep * WS_REP_BYTES + (size_t)kt * 32768;
    const int tid = threadIdx.x;
    #pragma unroll
    for (int ii = 0; ii < 8; ++ii) {
        const int gi  = tid + 256 * ii;               // 0..2047
        const int mr5 = gi >> 8, g = (gi >> 5) & 7, l = gi & 31;
        const float* sp = x + (size_t)(mr5 * 32 + l) * 2048 + kt * 64 + g * 8;
        f32x4 v0 = *(const f32x4*)sp, v1 = *(const f32x4*)(sp + 4);
        bf16x8 o;
        #pragma unroll
        for (int c = 0; c < 4; ++c) { o[c] = (bf16_t)v0[c]; o[4 + c] = (bf16_t)v1[c]; }
        *(bf16x8*)(dst + gi * 16) = o;                // coalesced 16B stores
    }
}

// ---------------------------------------------------------------- pass 2 ----
__global__ __launch_bounds__(256, 3)    // VGPR cap ~170; 8KB LDS -> 3 blk/CU
void fused_dual(const char* __restrict__ ws,
                const float* __restrict__ W1,   // [4096,2048,4] fp32
                const float* __restrict__ fcW,  // [1000,2048] fp32
                const float* __restrict__ fcb,
                const float* __restrict__ b1,
                const float* __restrict__ W2,
                const float* __restrict__ b2,
                float* __restrict__ out)        // x1[256*1000] ++ x2[256*4096]
{
    __shared__ __align__(16) char lds[2][4096];   // B double buffer ONLY

    const int tid  = threadIdx.x;
    const int lane = tid & 63, w = tid >> 6;      // 4 waves
    const int l31  = lane & 31, half = lane >> 5;

    // XCD swizzle: 544 = 8 x 68, bijective.
    const int idx = blockIdx.x;
    const int wid = (idx & 7) * 68 + (idx >> 3);
    const bool is_fc = (wid >= 512);
    const int d   = wid;                 // decoder block: o in [d*8, d*8+8)
    const int fcI = wid - 512;           // fc block: cols [fcI*32, +32)

    const char* aRep = ws + (size_t)((idx & 7) >> 1) * WS_REP_BYTES;
    const int aoff = w * 8192 + half * 512 + l31 * 16;   // + i*4096 + ks*1024

    // ---- B staging maps (precomputed) ----
    // dec: thread t: o=(t>>5)&7, kg=(t>>2)&7, kp=t&3 -> loads
    //   W1[d*8+o][kt*64 + kg*8 + kp*2 + {0,1}][0..3] (2 contiguous f32x4);
    //   writes 4x b32: rows n=4o+h, byte n*128 + bslot(n,kg)*16 + kp*4.
    // fc: thread t: n=t>>3, kg=t&7 -> loads fcW[c0+n][kt*64+kg*8..+7];
    //   writes 1x b128 at n*128 + bslot(n,kg)*16.
    const float* bSrc;
    int bStep;
    int dwo[4];     // dec write offsets per h (static-indexed)
    int fcWoff = 0;
    if (is_fc) {
        const int n = tid >> 3, kg = tid & 7;
        int c = fcI * 32 + n; if (c > 999) c = 999;      // stores guarded
        bSrc = fcW + (size_t)c * 2048 + kg * 8;
        bStep = 64;
        fcWoff = n * 128 + bslot(n, kg) * 16;
        #pragma unroll
        for (int h = 0; h < 4; ++h) dwo[h] = 0;
    } else {
        const int o = (tid >> 5) & 7, kg = (tid >> 2) & 7, kp = tid & 3;
        bSrc = W1 + (size_t)(d * 8 + o) * 8192 + (kg * 8 + kp * 2) * 4;
        bStep = 256;
        #pragma unroll
        for (int h = 0; h < 4; ++h) {
            const int n = 4 * o + h;
            dwo[h] = n * 128 + bslot(n, kg) * 16 + kp * 4;
        }
    }

    // B-frag read offsets (conflict-free; 4 values, static-indexed)
    int bro[4];
    #pragma unroll
    for (int ks = 0; ks < 4; ++ks)
        bro[ks] = l31 * 128 + bslot(l31, ks * 2 + half) * 16;

    f32x16 acc[2];
    #pragma unroll
    for (int i = 0; i < 2; ++i)
        #pragma unroll
        for (int r = 0; r < 16; ++r) acc[i][r] = 0.f;

    bf16x8 aF0[8], aF1[8];
    f32x4  bR0[2], bR1[2];

    auto A_PF = [&](int kt, bf16x8* F) {
        const char* ap = aRep + (size_t)kt * 32768 + aoff;
        #pragma unroll
        for (int i = 0; i < 2; ++i)
            #pragma unroll
            for (int ks = 0; ks < 4; ++ks)
                F[i * 4 + ks] = *(const bf16x8*)(ap + i * 4096 + ks * 1024);
    };
    auto B_LOAD = [&](int kt, f32x4* R) {
        const float* p = bSrc + (size_t)kt * bStep;
        R[0] = *(const f32x4*)p;
        R[1] = *(const f32x4*)(p + 4);
    };
    auto B_WRITE = [&](const f32x4* R, char* lB) {
        if (is_fc) {
            bf16x8 v;
            #pragma unroll
            for (int j = 0; j < 4; ++j) { v[j] = (bf16_t)R[0][j]; v[4 + j] = (bf16_t)R[1][j]; }
            *(bf16x8*)(lB + fcWoff) = v;
        } else {
            #pragma unroll
            for (int h = 0; h < 4; ++h) {
                bf16x2v v;
                v[0] = (bf16_t)R[0][h];               // k even
                v[1] = (bf16_t)R[1][h];               // k odd
                *(bf16x2v*)(lB + dwo[h]) = v;
            }
        }
    };
    auto MM = [&](const bf16x8* F, const char* lB) {
        #pragma unroll
        for (int ks = 0; ks < 4; ++ks) {
            bf16x8 bf = *(const bf16x8*)(lB + bro[ks]);
            #pragma unroll
            for (int i = 0; i < 2; ++i)
                acc[i] = __builtin_amdgcn_mfma_f32_32x32x16_bf16(F[i * 4 + ks], bf, acc[i], 0, 0, 0);
        }
    };

    // ---- prologue: B(0),B(1) in regs; A(0) in regs; B(0) -> lds[0]
    B_LOAD(0, bR0);
    B_LOAD(1, bR1);
    A_PF(0, aF0);
    B_WRITE(bR0, lds[0]);                   // compiler vmcnt-waits bR0 only
    asm volatile("s_waitcnt lgkmcnt(0)" ::: "memory");
    __builtin_amdgcn_s_barrier();
    asm volatile("" ::: "memory");

    // ---- main loop: 32 k-tiles, hand-unrolled x2 (static reg naming)
    for (int t2 = 0; t2 < 16; ++t2) {
        const int t = t2 * 2;
        // even iter t: compute lds[0]/aF0; stage B(t+1)->lds[1]; pf A(t+1),B(t+2)
        {
            A_PF(t + 1, aF1);
            int kb = t + 2; if (kb > 31) kb = 31;      // tail clamp (harmless)
            B_LOAD(kb, bR0);
            MM(aF0, lds[0]);
            B_WRITE(bR1, lds[1]);
            asm volatile("s_waitcnt lgkmcnt(0)" ::: "memory");
            __builtin_amdgcn_s_barrier();
            asm volatile("" ::: "memory");
        }
        // odd iter t+1: compute lds[1]/aF1; stage B(t+2)->lds[0]; pf A(t+2),B(t+3)
        {
            int ka = t + 2; if (ka > 31) ka = 31;
            A_PF(ka, aF0);
            int kb = t + 3; if (kb > 31) kb = 31;
            B_LOAD(kb, bR1);
            MM(aF1, lds[1]);
            B_WRITE(bR0, lds[0]);
            asm volatile("s_waitcnt lgkmcnt(0)" ::: "memory");
            __builtin_amdgcn_s_barrier();
            asm volatile("" ::: "memory");
        }
    }

    // ---- epilogue ----  C/D: col=lane&31, row=(r&3)+8*(r>>2)+4*half
    if (is_fc) {
        const int c = fcI * 32 + l31;
        if (c < 1000) {
            const float bias = fcb[c];
            #pragma unroll
            for (int i = 0; i < 2; ++i)
            #pragma unroll
            for (int r = 0; r < 16; ++r) {
                const int m = w * 64 + i * 32 + (r & 3) + 8 * (r >> 2) + 4 * half;
                out[m * 1000 + c] = acc[i][r] + bias;
            }
        }
    } else {
        float* x2 = out + 256 * 1000;
        const int n_glob = d * 32 + l31;              // = (d*8+o)*4 + h
        const float b1v = b1[n_glob], w2v = W2[n_glob];
        const float b2v = b2[n_glob >> 2];
        float* xs = (float*)lds;                      // [256 rows][8 o] = 8KB
        const int o8 = l31 >> 2;
        #pragma unroll
        for (int i = 0; i < 2; ++i)
        #pragma unroll
        for (int r = 0; r < 16; ++r) {
            float h = acc[i][r] + b1v;
            h = (h >= 0.f) ? h : 0.1f * h;            // leaky relu
            float wv = h * w2v;
            wv += __shfl_xor(wv, 1, 64);              // decoder's 4 h-cols
            wv += __shfl_xor(wv, 2, 64);
            if ((lane & 3) == 0) {
                const int row = w * 64 + i * 32 + (r & 3) + 8 * (r >> 2) + 4 * half;
                xs[row * 8 + o8] = wv + b2v;
            }
        }
        __syncthreads();
        #pragma unroll
        for (int j = 0; j < 2; ++j) {
            const int row = (tid >> 1) + j * 128, part = tid & 1;
            f32x4 v = *(const f32x4*)(xs + row * 8 + part * 4);
            *(f32x4*)(x2 + (size_t)row * 4096 + d * 8 + part * 4) = v;
        }
    }
}

extern "C" void kernel_launch(void* const* d_in, const int* in_sizes, int n_in,
                              void* d_out, int out_size, void* d_ws, size_t ws_size,
                              hipStream_t stream)
{
    (void)in_sizes; (void)n_in; (void)out_size; (void)ws_size;
    const float* x   = (const float*)d_in[0];
    const float* fcW = (const float*)d_in[1];
    const float* fcb = (const float*)d_in[2];
    const float* W1  = (const float*)d_in[3];
    const float* b1  = (const float*)d_in[4];
    const float* W2  = (const float*)d_in[5];
    const float* b2  = (const float*)d_in[6];
    char* ws = (char*)d_ws;                       // 4 MB (< proven-safe 5 MB)
    pack_a<<<128, 256, 0, stream>>>(x, ws);
    fused_dual<<<544, 256, 0, stream>>>(ws, W1, fcW, fcb, b1, W2, b2, (float*)d_out);
}